// Round 15
// baseline (2651.940 us; speedup 1.0000x reference)
//
#include <hip/hip_runtime.h>
#include <hip/hip_bf16.h>

// B=8192, T=32, D_IN=2, EMB=128, H=256, 4H=1024
// r15 = r12 two-phase split at 512 blocks x 512 threads (8 waves), 16 rows/blk.
// Bet: miss-bytes ~invariant to block count (r12<->r13 evidence) while service
// rate rises with concurrency; 2-3 blocks/CU co-resident (LDS ~46KB/blk).
// Wave owns col-tiles T=wid and wid+8 (16 cols each per gate); acc=[4q][2T].
// Ring: 4 slots, depth 3, counted vmcnt(3), wrap mod 96 (l0) / 128 (l1).

typedef __attribute__((ext_vector_type(8))) __bf16 bf16x8;
typedef __attribute__((ext_vector_type(4))) __bf16 bf16x4;
typedef __attribute__((ext_vector_type(4))) float f32x4;

#define MFMA16(a, b, c) __builtin_amdgcn_mfma_f32_16x16x32_bf16(a, b, c, 0, 0, 0)

// s_waitcnt imm (gfx9): vmcnt[3:0]|[15:14], expcnt[6:4], lgkm[11:8]
#define WAIT_VM3() __builtin_amdgcn_s_waitcnt(0xF73)
#define WAIT_LGKM0() __builtin_amdgcn_s_waitcnt(0xC07F)
#define RAW_BARRIER()                  \
  do {                                 \
    WAIT_LGKM0();                      \
    __builtin_amdgcn_sched_barrier(0); \
    __builtin_amdgcn_s_barrier();      \
  } while (0)

__device__ __forceinline__ float fexp2(float x) {
#if __has_builtin(__builtin_amdgcn_exp2f)
  return __builtin_amdgcn_exp2f(x);
#else
  return exp2f(x);
#endif
}
__device__ __forceinline__ float frcp(float x) {
#if __has_builtin(__builtin_amdgcn_rcpf)
  return __builtin_amdgcn_rcpf(x);
#else
  return 1.0f / x;
#endif
}
__device__ __forceinline__ float fsig(float x) {
  return frcp(1.0f + fexp2(-1.44269504f * x));
}
__device__ __forceinline__ float ftanh(float x) {
  return 1.0f - 2.0f * frcp(1.0f + fexp2(2.88539008f * x));
}

// ---- weight prep: swizzle [W;U] (K x 1024) fp32 -> per-frag bf16 order ----
// frag g = T*48 + q*12 + kc (l0) / T*64 + q*16 + kcx (l1); T = col-tile 0..15,
// tile cols = q*256 + (T>>2)*64 + (T&3)*16 + (l&15)
__global__ void prep_w0(const float* __restrict__ W0, const float* __restrict__ U0,
                        __bf16* __restrict__ o) {
  const int f = blockIdx.x * 256 + threadIdx.x;  // < 393216
  const int j = f & 7, l5 = (f >> 3) & 63, g = f >> 9;
  const int kc = g % 12, q = (g / 12) & 3, T = g / 48;
  const int k = (kc << 5) + ((l5 >> 4) << 3) + j;
  const int c = (q << 8) + ((T >> 2) << 6) + ((T & 3) << 4) + (l5 & 15);
  const float v = (k < 128) ? W0[(k << 10) + c] : U0[((k - 128) << 10) + c];
  o[f] = (__bf16)v;
}
__global__ void prep_w1(const float* __restrict__ W1, const float* __restrict__ U1,
                        __bf16* __restrict__ o) {
  const int f = blockIdx.x * 256 + threadIdx.x;  // < 524288
  const int j = f & 7, l5 = (f >> 3) & 63, g = f >> 9;
  const int kcx = g & 15, q = (g >> 4) & 3, T = g >> 6;
  const int k = (kcx << 5) + ((l5 >> 4) << 3) + j;
  const int c = (q << 8) + ((T >> 2) << 6) + ((T & 3) << 4) + (l5 & 15);
  const float v = (k < 256) ? W1[(k << 10) + c] : U1[((k - 256) << 10) + c];
  o[f] = (__bf16)v;
}

// ============================ phase 0: layer 0 =============================
__global__ __launch_bounds__(512)
void lstm_l0(const float* __restrict__ traj,
             const float* __restrict__ Wemb,
             const float* __restrict__ bemb,
             const float* __restrict__ bias0,
             const __bf16* __restrict__ wb0,
             float* __restrict__ out,
             __bf16* __restrict__ slab) {
  __shared__ float s_We[384];
  __shared__ float s_traj[1024];    // [t][r][d]: t*32 + r*2 + d (16 rows)
  __shared__ __bf16 s_h0[4096];     // 16 rows x 256, swizzled
  __shared__ __bf16 s_ring[16384];  // 8 waves x 4 slots x 512 (32 KB)

  const int tid = threadIdx.x;
  const int wid = tid >> 6;  // 0..7
  const int l = tid & 63;
  const int lr = l & 15, lg = l >> 4;
  const int xr = (lr & 7) << 3;
  const int r0 = blockIdx.x << 4;  // 16 rows/block
  // wave col-tiles T1=wid, T2=wid+8; e (within gate) bases:
  const int eT1 = ((wid >> 2) << 6) + ((wid & 3) << 4);
  const int e0a = eT1 + (lg << 2);
  const int e0b = e0a + 128;  // tile T2 = T1 + 128 cols

  if (tid < 384) s_We[tid] = (tid < 256) ? Wemb[tid] : bemb[tid - 256];
  for (int i = tid; i < 1024; i += 512) {
    const int r = i >> 6, tt = (i >> 1) & 31, d = i & 1;
    s_traj[(tt << 5) + (r << 1) + d] = traj[(r0 << 6) + i];
  }
  for (int i = tid; i < 4096; i += 512) s_h0[i] = (__bf16)0.f;
  __syncthreads();

  float c0s[2][4] = {};  // [tile2][i]
  __bf16* ringp = &s_ring[wid << 11];  // 4 slots x 512

  // cf = kc*8 + tile2*4 + q in [0,96)
  auto stage = [&](int cf) {
    const int kc = cf >> 3, tile2 = (cf >> 2) & 1, q = cf & 3;
    const __bf16* src =
        wb0 + (((wid + (tile2 << 3)) * 48 + q * 12 + kc) << 9) + (l << 3);
    __builtin_amdgcn_global_load_lds(
        (const __attribute__((address_space(1))) void*)src,
        (__attribute__((address_space(3))) void*)(ringp + ((cf & 3) << 9)),
        16, 0, 0);
  };
  auto ring_read = [&](int cf) {
    return *reinterpret_cast<const bf16x8*>(ringp + ((cf & 3) << 9) + (l << 3));
  };

  stage(0); stage(1); stage(2);

#pragma unroll 1
  for (int t = 0; t < 32; ++t) {
    f32x4 acc[4][2];  // [q][tile2]
#pragma unroll
    for (int q = 0; q < 4; ++q) {
      acc[q][0] = *reinterpret_cast<const f32x4*>(bias0 + (q << 8) + e0a);
      acc[q][1] = *reinterpret_cast<const f32x4*>(bias0 + (q << 8) + e0b);
    }
    const float t0v = s_traj[(t << 5) + (lr << 1)];
    const float t1v = s_traj[(t << 5) + (lr << 1) + 1];
#pragma unroll
    for (int kc = 0; kc < 12; ++kc) {
      bf16x8 ia;
      if (kc < 4) {  // x-part on the fly
#pragma unroll
        for (int j = 0; j < 8; ++j) {
          const int k = (kc << 5) + (lg << 3) + j;
          const float x =
              fmaf(t0v, s_We[k], fmaf(t1v, s_We[128 + k], s_We[256 + k]));
          ia[j] = (__bf16)fmaxf(x, 0.f);
        }
      } else {
        ia = *reinterpret_cast<const bf16x8*>(
            &s_h0[(lr << 8) + ((((kc - 4) << 5) + (lg << 3)) ^ xr)]);
      }
#pragma unroll
      for (int c8 = 0; c8 < 8; ++c8) {
        const int cf = (kc << 3) + c8;
        const int tile2 = (cf >> 2) & 1, q = cf & 3;
        stage((cf + 3) % 96);
        WAIT_VM3();
        __builtin_amdgcn_sched_barrier(0);
        const bf16x8 wf = ring_read(cf);
        acc[q][tile2] = MFMA16(wf, ia, acc[q][tile2]);
      }
    }
    RAW_BARRIER();  // all s_h0 reads done
#pragma unroll
    for (int tile2 = 0; tile2 < 2; ++tile2) {
      const int e0 = tile2 ? e0b : e0a;
      bf16x4 hv;
      f32x4 cfv;
#pragma unroll
      for (int i = 0; i < 4; ++i) {
        const float cc = fsig(acc[1][tile2][i]) * c0s[tile2][i] +
                         fsig(acc[0][tile2][i]) * ftanh(acc[2][tile2][i]);
        c0s[tile2][i] = cc;
        hv[i] = (__bf16)(fsig(acc[3][tile2][i]) * ftanh(cc));
        cfv[i] = cc;
      }
      *reinterpret_cast<bf16x4*>(&s_h0[(lr << 8) + (e0 ^ xr)]) = hv;
      if (t == 31) {  // c0 final
        *reinterpret_cast<f32x4*>(out + 69206016 + ((r0 + lr) << 8) + e0) = cfv;
      }
    }
    RAW_BARRIER();  // h0(t) complete in LDS

    // slab copy: wave writes rows 2wid, 2wid+1 as full 512B lines (de-swizzled)
#pragma unroll
    for (int rr = 0; rr < 2; ++rr) {
      const int row = (wid << 1) + rr;
      const bf16x4 hv4 = *reinterpret_cast<const bf16x4*>(
          &s_h0[(row << 8) + ((l << 2) ^ ((row & 7) << 3))]);
      *reinterpret_cast<bf16x4*>(
          slab + ((size_t)(t * 8192 + r0 + row) << 8) + (l << 2)) = hv4;
      if (t == 31) {  // h0 final (fp32, full-line)
        f32x4 v;
#pragma unroll
        for (int i = 0; i < 4; ++i) v[i] = (float)hv4[i];
        *reinterpret_cast<f32x4*>(out + 67108864 + ((r0 + row) << 8) + (l << 2)) = v;
      }
    }
    // no barrier: s_h0 next written at t+1 epilogue, behind its RAW_BARRIERs
  }
}

// ============================ phase 1: layer 1 =============================
__global__ __launch_bounds__(512)
void lstm_l1(const float* __restrict__ bias1,
             const __bf16* __restrict__ wb1,
             const __bf16* __restrict__ slab,
             float* __restrict__ out) {
  __shared__ __bf16 s_h0[4096];     // staged h0(t), swizzled (8 KB)
  __shared__ __bf16 s_h1[4096];     // 8 KB
  __shared__ __bf16 s_ring[16384];  // 32 KB

  const int tid = threadIdx.x;
  const int wid = tid >> 6;  // 0..7
  const int l = tid & 63;
  const int lr = l & 15, lg = l >> 4;
  const int xr = (lr & 7) << 3;
  const int r0 = blockIdx.x << 4;
  const int eT1 = ((wid >> 2) << 6) + ((wid & 3) << 4);
  const int e0a = eT1 + (lg << 2);
  const int e0b = e0a + 128;

  for (int i = tid; i < 4096; i += 512) s_h1[i] = (__bf16)0.f;
  __syncthreads();

  float c1s[2][4] = {};
  __bf16* ringp = &s_ring[wid << 11];

  // cf = it8*8 + tile2*4 + q in [0,128); kcx = it8^8
  // (it8 0..7 -> kcx 8..15 = U1/h1 part; it8 8..15 -> kcx 0..7 = W1/h0 part)
  auto stage = [&](int cf) {
    const int it8 = (cf >> 3) & 15, tile2 = (cf >> 2) & 1, q = cf & 3;
    const int kcx = it8 ^ 8;
    const __bf16* src =
        wb1 + (((wid + (tile2 << 3)) * 64 + (q << 4) + kcx) << 9) + (l << 3);
    __builtin_amdgcn_global_load_lds(
        (const __attribute__((address_space(1))) void*)src,
        (__attribute__((address_space(3))) void*)(ringp + ((cf & 3) << 9)),
        16, 0, 0);
  };
  auto ring_read = [&](int cf) {
    return *reinterpret_cast<const bf16x8*>(ringp + ((cf & 3) << 9) + (l << 3));
  };

  // ingest addressing: wave ingests rows 2wid, 2wid+1 (1KB = one gload_lds)
  const int irow = (wid << 1) + (l >> 5);
  const int iwb = (l & 31) << 4;  // within-row byte
  const size_t ioff =
      ((size_t)(r0 + irow) << 8) + ((iwb ^ ((irow & 7) << 4)) >> 1);  // elems

  stage(0); stage(1); stage(2);

#pragma unroll 1
  for (int t = 0; t < 32; ++t) {
    // ingest h0(t): pre-swizzled source -> linear LDS dest
    __builtin_amdgcn_global_load_lds(
        (const __attribute__((address_space(1))) void*)(slab +
            (((size_t)t * 8192) << 8) + ioff),
        (__attribute__((address_space(3))) void*)(s_h0 + (wid << 9)),
        16, 0, 0);

    f32x4 acc[4][2];
#pragma unroll
    for (int q = 0; q < 4; ++q) {
      acc[q][0] = *reinterpret_cast<const f32x4*>(bias1 + (q << 8) + e0a);
      acc[q][1] = *reinterpret_cast<const f32x4*>(bias1 + (q << 8) + e0b);
    }
    // ---- h1 part (kcx 8..15) ----
#pragma unroll
    for (int it8 = 0; it8 < 8; ++it8) {
      const bf16x8 ib = *reinterpret_cast<const bf16x8*>(
          &s_h1[(lr << 8) + (((it8 << 5) + (lg << 3)) ^ xr)]);
#pragma unroll
      for (int c8 = 0; c8 < 8; ++c8) {
        const int cf = (it8 << 3) + c8;
        const int tile2 = (cf >> 2) & 1, q = cf & 3;
        stage((cf + 3) % 128);
        WAIT_VM3();
        __builtin_amdgcn_sched_barrier(0);
        const bf16x8 wf = ring_read(cf);
        acc[q][tile2] = MFMA16(wf, ib, acc[q][tile2]);
      }
    }
    // ingest retired (64 counted waits since issue); publish before h0 reads
    RAW_BARRIER();
    // ---- h0 part (kcx 0..7) ----
#pragma unroll
    for (int it8 = 8; it8 < 16; ++it8) {
      const int kcl = it8 - 8;
      const bf16x8 ib = *reinterpret_cast<const bf16x8*>(
          &s_h0[(lr << 8) + (((kcl << 5) + (lg << 3)) ^ xr)]);
#pragma unroll
      for (int c8 = 0; c8 < 8; ++c8) {
        const int cf = (it8 << 3) + c8;
        const int tile2 = (cf >> 2) & 1, q = cf & 3;
        stage((cf + 3) % 128);
        WAIT_VM3();
        __builtin_amdgcn_sched_barrier(0);
        const bf16x8 wf = ring_read(cf);
        acc[q][tile2] = MFMA16(wf, ib, acc[q][tile2]);
      }
    }
    RAW_BARRIER();  // all s_h1 reads done
#pragma unroll
    for (int tile2 = 0; tile2 < 2; ++tile2) {
      const int e0 = tile2 ? e0b : e0a;
      bf16x4 hv;
      f32x4 cfv;
#pragma unroll
      for (int i = 0; i < 4; ++i) {
        const float cc = fsig(acc[1][tile2][i]) * c1s[tile2][i] +
                         fsig(acc[0][tile2][i]) * ftanh(acc[2][tile2][i]);
        c1s[tile2][i] = cc;
        hv[i] = (__bf16)(fsig(acc[3][tile2][i]) * ftanh(cc));
        cfv[i] = cc;
      }
      *reinterpret_cast<bf16x4*>(&s_h1[(lr << 8) + (e0 ^ xr)]) = hv;
      if (t == 31) {  // c1 final
        *reinterpret_cast<f32x4*>(out + 73400320 + ((r0 + lr) << 8) + e0) = cfv;
      }
    }
    RAW_BARRIER();  // h1(t) complete in LDS

    // y write: wave writes rows 2wid, 2wid+1, one full 1KB row per instruction
#pragma unroll
    for (int j = 0; j < 2; ++j) {
      const int row = (wid << 1) + j;
      const int xw = (row & 7) << 3;
      const bf16x4 a =
          *reinterpret_cast<const bf16x4*>(&s_h1[(row << 8) + ((l << 2) ^ xw)]);
      f32x4 v;
#pragma unroll
      for (int i = 0; i < 4; ++i) v[i] = (float)a[i];
      *reinterpret_cast<f32x4*>(out + ((((r0 + row) << 5) + t) << 8) + (l << 2)) = v;
      if (t == 31) {  // h1 final = y[:,31,:]
        *reinterpret_cast<f32x4*>(out + 71303168 + ((r0 + row) << 8) + (l << 2)) = v;
      }
    }
    // next-iter ingest targets s_h0 (not read until after next RAW_BARRIER
    // chain); s_h1 rows just read are not rewritten until next epilogue.
  }
}

extern "C" void kernel_launch(void* const* d_in, const int* in_sizes, int n_in,
                              void* d_out, int out_size, void* d_ws, size_t ws_size,
                              hipStream_t stream) {
  const float* traj = (const float*)d_in[0];
  const float* Wemb = (const float*)d_in[1];
  const float* bemb = (const float*)d_in[2];
  const float* W0 = (const float*)d_in[3];
  const float* U0 = (const float*)d_in[4];
  const float* b0 = (const float*)d_in[5];
  const float* W1 = (const float*)d_in[6];
  const float* U1 = (const float*)d_in[7];
  const float* b1 = (const float*)d_in[8];
  float* out = (float*)d_out;

  __bf16* wb0 = (__bf16*)d_ws;  // 768 KB
  __bf16* wb1 = wb0 + 393216;   // 1 MB
  const size_t slab_off = 1835008;
  __bf16* slab = (__bf16*)((char*)d_ws + slab_off);  // 134 MB

  hipLaunchKernelGGL(prep_w0, dim3(1536), dim3(256), 0, stream, W0, U0, wb0);
  hipLaunchKernelGGL(prep_w1, dim3(2048), dim3(256), 0, stream, W1, U1, wb1);
  hipLaunchKernelGGL(lstm_l0, dim3(512), dim3(512), 0, stream,
                     traj, Wemb, bemb, b0, wb0, out, slab);
  hipLaunchKernelGGL(lstm_l1, dim3(512), dim3(512), 0, stream,
                     b1, wb1, slab, out);
}

// Round 16
// 1381.987 us; speedup vs baseline: 1.9189x; 1.9189x over previous
//
#include <hip/hip_runtime.h>
#include <hip/hip_bf16.h>

// B=8192, T=32, D_IN=2, EMB=128, H=256, 4H=1024
// r16 = r12 (two-phase, 256 blk x 32 rows x 1024 thr, best 1379us) + NT policy:
// every non-weight stream is non-temporal (no L2 allocate) so the weight set
// is the only L2 insertion -> tip the thrash equilibrium to weights-resident.
//   l0: slab writes + h0/c0 finals NT-stores.
//   l1: slab ingest via global_load_lds aux=2 (NT); y + h1/c1 finals NT-stores.
// Weight stages keep aux=0 (allocate). Ring: 4 slots, depth 3, vmcnt(3).

typedef __attribute__((ext_vector_type(8))) __bf16 bf16x8;
typedef __attribute__((ext_vector_type(4))) __bf16 bf16x4;
typedef __attribute__((ext_vector_type(4))) float f32x4;

#define MFMA16(a, b, c) __builtin_amdgcn_mfma_f32_16x16x32_bf16(a, b, c, 0, 0, 0)

// s_waitcnt imm (gfx9): vmcnt[3:0]|[15:14], expcnt[6:4], lgkm[11:8]
#define WAIT_VM3() __builtin_amdgcn_s_waitcnt(0xF73)
#define WAIT_LGKM0() __builtin_amdgcn_s_waitcnt(0xC07F)
#define RAW_BARRIER()                  \
  do {                                 \
    WAIT_LGKM0();                      \
    __builtin_amdgcn_sched_barrier(0); \
    __builtin_amdgcn_s_barrier();      \
  } while (0)

__device__ __forceinline__ float fexp2(float x) {
#if __has_builtin(__builtin_amdgcn_exp2f)
  return __builtin_amdgcn_exp2f(x);
#else
  return exp2f(x);
#endif
}
__device__ __forceinline__ float frcp(float x) {
#if __has_builtin(__builtin_amdgcn_rcpf)
  return __builtin_amdgcn_rcpf(x);
#else
  return 1.0f / x;
#endif
}
__device__ __forceinline__ float fsig(float x) {
  return frcp(1.0f + fexp2(-1.44269504f * x));
}
__device__ __forceinline__ float ftanh(float x) {
  return 1.0f - 2.0f * frcp(1.0f + fexp2(2.88539008f * x));
}

// ---- weight prep: swizzle [W;U] (K x 1024) fp32 -> per-frag bf16 order ----
__global__ void prep_w0(const float* __restrict__ W0, const float* __restrict__ U0,
                        __bf16* __restrict__ o) {
  const int f = blockIdx.x * 256 + threadIdx.x;  // < 393216
  const int j = f & 7, l5 = (f >> 3) & 63, g = f >> 9;
  const int kc = g % 12, q = (g / 12) & 3, wid = g / 48;
  const int k = (kc << 5) + ((l5 >> 4) << 3) + j;
  const int c = (q << 8) + ((wid >> 2) << 6) + ((wid & 3) << 4) + (l5 & 15);
  const float v = (k < 128) ? W0[(k << 10) + c] : U0[((k - 128) << 10) + c];
  o[f] = (__bf16)v;
}
__global__ void prep_w1(const float* __restrict__ W1, const float* __restrict__ U1,
                        __bf16* __restrict__ o) {
  const int f = blockIdx.x * 256 + threadIdx.x;  // < 524288
  const int j = f & 7, l5 = (f >> 3) & 63, g = f >> 9;
  const int kcx = g & 15, q = (g >> 4) & 3, wid = g >> 6;
  const int k = (kcx << 5) + ((l5 >> 4) << 3) + j;
  const int c = (q << 8) + ((wid >> 2) << 6) + ((wid & 3) << 4) + (l5 & 15);
  const float v = (k < 256) ? W1[(k << 10) + c] : U1[((k - 256) << 10) + c];
  o[f] = (__bf16)v;
}

// ============================ phase 0: layer 0 =============================
__global__ __launch_bounds__(1024)
void lstm_l0(const float* __restrict__ traj,
             const float* __restrict__ Wemb,
             const float* __restrict__ bemb,
             const float* __restrict__ bias0,
             const __bf16* __restrict__ wb0,
             float* __restrict__ out,
             __bf16* __restrict__ slab) {
  __shared__ float s_We[384];
  __shared__ float s_b[1024];
  __shared__ float s_traj[2048];    // [t][r][d]: t*64 + r*2 + d (32 rows)
  __shared__ __bf16 s_h0[8192];     // 32 rows x 256, swizzled
  __shared__ __bf16 s_ring[32768];  // 16 waves x 4 slots x 512

  const int tid = threadIdx.x;
  const int wid = tid >> 6;
  const int l = tid & 63;
  const int lr = l & 15, lg = l >> 4;
  const int w = wid >> 2, s4 = wid & 3;
  const int xr = (lr & 7) << 3;
  const int r0 = blockIdx.x << 5;
  const int e0 = (w << 6) + (s4 << 4) + (lg << 2);

  if (tid < 384) s_We[tid] = (tid < 256) ? Wemb[tid] : bemb[tid - 256];
  {
    const int ct = tid >> 4, cc = tid & 15;
    const int wd = ct >> 2, q = ct & 3;
    const int col = (q << 8) + ((wd >> 2) << 6) + ((wd & 3) << 4) + cc;
    s_b[tid] = bias0[col];
  }
  for (int i = tid; i < 2048; i += 1024) {
    const int r = i >> 6, tt = (i >> 1) & 31, d = i & 1;
    s_traj[(tt << 6) + (r << 1) + d] = traj[(r0 << 6) + i];
  }
  for (int i = tid; i < 8192; i += 1024) s_h0[i] = (__bf16)0.f;
  __syncthreads();

  float c0s[2][4] = {};
  const __bf16* wp0 = wb0 + wid * 48 * 512 + l * 8;
  __bf16* ringp = &s_ring[wid << 11];

  auto stage = [&](int cf) {  // cf = kc*4+q in [0,48)
    const __bf16* src = wp0 + (((cf & 3) * 12 + (cf >> 2)) << 9);
    __builtin_amdgcn_global_load_lds(
        (const __attribute__((address_space(1))) void*)src,
        (__attribute__((address_space(3))) void*)(ringp + ((cf & 3) << 9)),
        16, 0, 0);
  };
  auto ring_read = [&](int cf) {
    return *reinterpret_cast<const bf16x8*>(ringp + ((cf & 3) << 9) + (l << 3));
  };

  stage(0); stage(1); stage(2);

#pragma unroll 1
  for (int t = 0; t < 32; ++t) {
    f32x4 acc[4][2];
#pragma unroll
    for (int q = 0; q < 4; ++q) {
      const f32x4 b =
          *reinterpret_cast<const f32x4*>(&s_b[(((wid << 2) + q) << 4) + (lg << 2)]);
      acc[q][0] = b;
      acc[q][1] = b;
    }
    float t0v[2], t1v[2];
#pragma unroll
    for (int rt = 0; rt < 2; ++rt) {
      const int r = (rt << 4) + lr;
      t0v[rt] = s_traj[(t << 6) + (r << 1)];
      t1v[rt] = s_traj[(t << 6) + (r << 1) + 1];
    }
#pragma unroll
    for (int kc = 0; kc < 12; ++kc) {
      bf16x8 ia[2];
      if (kc < 4) {  // x-part on the fly
#pragma unroll
        for (int rt = 0; rt < 2; ++rt) {
#pragma unroll
          for (int j = 0; j < 8; ++j) {
            const int k = (kc << 5) + (lg << 3) + j;
            const float x = fmaf(t0v[rt], s_We[k],
                                 fmaf(t1v[rt], s_We[128 + k], s_We[256 + k]));
            ia[rt][j] = (__bf16)fmaxf(x, 0.f);
          }
        }
      } else {
#pragma unroll
        for (int rt = 0; rt < 2; ++rt) {
          const int r = (rt << 4) + lr;
          ia[rt] = *reinterpret_cast<const bf16x8*>(
              &s_h0[(r << 8) + ((((kc - 4) << 5) + (lg << 3)) ^ xr)]);
        }
      }
#pragma unroll
      for (int q = 0; q < 4; ++q) {
        const int cf = (kc << 2) + q;
        stage((cf + 3) % 48);
        WAIT_VM3();
        __builtin_amdgcn_sched_barrier(0);
        const bf16x8 wf = ring_read(cf);
        acc[q][0] = MFMA16(wf, ia[0], acc[q][0]);
        acc[q][1] = MFMA16(wf, ia[1], acc[q][1]);
      }
    }
    RAW_BARRIER();  // all s_h0 reads done
#pragma unroll
    for (int rt = 0; rt < 2; ++rt) {
      const int r = (rt << 4) + lr;
      bf16x4 hv;
      f32x4 cfv;
#pragma unroll
      for (int i = 0; i < 4; ++i) {
        const float cc = fsig(acc[1][rt][i]) * c0s[rt][i] +
                         fsig(acc[0][rt][i]) * ftanh(acc[2][rt][i]);
        c0s[rt][i] = cc;
        hv[i] = (__bf16)(fsig(acc[3][rt][i]) * ftanh(cc));
        cfv[i] = cc;
      }
      *reinterpret_cast<bf16x4*>(&s_h0[(r << 8) + (e0 ^ xr)]) = hv;
      if (t == 31) {  // c0 final (NT)
        __builtin_nontemporal_store(
            cfv, reinterpret_cast<f32x4*>(out + 69206016 + ((r0 + r) << 8) + e0));
      }
    }
    RAW_BARRIER();  // h0(t) complete in LDS

    // slab copy: wave writes rows 2wid, 2wid+1 as full 512B lines (NT)
#pragma unroll
    for (int rr = 0; rr < 2; ++rr) {
      const int row = (wid << 1) + rr;
      const bf16x4 hv4 = *reinterpret_cast<const bf16x4*>(
          &s_h0[(row << 8) + ((l << 2) ^ ((row & 7) << 3))]);
      __builtin_nontemporal_store(
          hv4, reinterpret_cast<bf16x4*>(
                   slab + ((size_t)(t * 8192 + r0 + row) << 8) + (l << 2)));
      if (t == 31) {  // h0 final (fp32, full-line, NT)
        f32x4 v;
#pragma unroll
        for (int i = 0; i < 4; ++i) v[i] = (float)hv4[i];
        __builtin_nontemporal_store(
            v, reinterpret_cast<f32x4*>(out + 67108864 + ((r0 + row) << 8) + (l << 2)));
      }
    }
    // no barrier: s_h0 next written at t+1 epilogue, behind its RAW_BARRIERs
  }
}

// ============================ phase 1: layer 1 =============================
__global__ __launch_bounds__(1024)
void lstm_l1(const float* __restrict__ bias1,
             const __bf16* __restrict__ wb1,
             const __bf16* __restrict__ slab,
             float* __restrict__ out) {
  __shared__ float s_b[1024];
  __shared__ __bf16 s_h0[8192];     // staged h0(t), swizzled
  __shared__ __bf16 s_h1[8192];
  __shared__ __bf16 s_ring[32768];

  const int tid = threadIdx.x;
  const int wid = tid >> 6;
  const int l = tid & 63;
  const int lr = l & 15, lg = l >> 4;
  const int w = wid >> 2, s4 = wid & 3;
  const int xr = (lr & 7) << 3;
  const int r0 = blockIdx.x << 5;
  const int e0 = (w << 6) + (s4 << 4) + (lg << 2);

  {
    const int ct = tid >> 4, cc = tid & 15;
    const int wd = ct >> 2, q = ct & 3;
    const int col = (q << 8) + ((wd >> 2) << 6) + ((wd & 3) << 4) + cc;
    s_b[tid] = bias1[col];
  }
  for (int i = tid; i < 8192; i += 1024) s_h1[i] = (__bf16)0.f;
  __syncthreads();

  float c1s[2][4] = {};
  const __bf16* wp1 = wb1 + wid * 64 * 512 + l * 8;
  __bf16* ringp = &s_ring[wid << 11];

  // consumption order: it8 0..7 -> kcx 8..15 (U1/h1 part), it8 8..15 -> kcx 0..7
  auto stage = [&](int cf) {  // cf = it8*4+q in [0,64)
    const int it8 = (cf >> 2) & 15, q = cf & 3;
    const int kcx = it8 ^ 8;
    const __bf16* src = wp1 + (((q << 4) + kcx) << 9);
    __builtin_amdgcn_global_load_lds(
        (const __attribute__((address_space(1))) void*)src,
        (__attribute__((address_space(3))) void*)(ringp + ((cf & 3) << 9)),
        16, 0, 0);
  };
  auto ring_read = [&](int cf) {
    return *reinterpret_cast<const bf16x8*>(ringp + ((cf & 3) << 9) + (l << 3));
  };

  // ingest addressing: wave ingests rows 2wid, 2wid+1 (1KB = one gload_lds)
  const int irow = (wid << 1) + (l >> 5);
  const int iwb = (l & 31) << 4;  // within-row byte
  const size_t ioff =
      ((size_t)(r0 + irow) << 8) + ((iwb ^ ((irow & 7) << 4)) >> 1);  // elems

  stage(0); stage(1); stage(2);

#pragma unroll 1
  for (int t = 0; t < 32; ++t) {
    // ingest h0(t): pre-swizzled source -> linear LDS dest; aux=2 => NT load
    __builtin_amdgcn_global_load_lds(
        (const __attribute__((address_space(1))) void*)(slab +
            (((size_t)t * 8192) << 8) + ioff),
        (__attribute__((address_space(3))) void*)(s_h0 + (wid << 9)),
        16, 0, 2);

    f32x4 acc[4][2];
#pragma unroll
    for (int q = 0; q < 4; ++q) {
      const f32x4 b =
          *reinterpret_cast<const f32x4*>(&s_b[(((wid << 2) + q) << 4) + (lg << 2)]);
      acc[q][0] = b;
      acc[q][1] = b;
    }
    // ---- h1 part (kcx 8..15) ----
#pragma unroll
    for (int it8 = 0; it8 < 8; ++it8) {
      bf16x8 ib[2];
#pragma unroll
      for (int rt = 0; rt < 2; ++rt) {
        const int r = (rt << 4) + lr;
        ib[rt] = *reinterpret_cast<const bf16x8*>(
            &s_h1[(r << 8) + (((it8 << 5) + (lg << 3)) ^ xr)]);
      }
#pragma unroll
      for (int q = 0; q < 4; ++q) {
        const int cf = (it8 << 2) + q;
        stage((cf + 3) % 64);
        WAIT_VM3();
        __builtin_amdgcn_sched_barrier(0);
        const bf16x8 wf = ring_read(cf);
        acc[q][0] = MFMA16(wf, ib[0], acc[q][0]);
        acc[q][1] = MFMA16(wf, ib[1], acc[q][1]);
      }
    }
    // ingest retired (32 counted waits since issue); publish before h0 reads
    RAW_BARRIER();
    // ---- h0 part (kcx 0..7) ----
#pragma unroll
    for (int it8 = 8; it8 < 16; ++it8) {
      const int kcl = it8 - 8;
      bf16x8 ib[2];
#pragma unroll
      for (int rt = 0; rt < 2; ++rt) {
        const int r = (rt << 4) + lr;
        ib[rt] = *reinterpret_cast<const bf16x8*>(
            &s_h0[(r << 8) + (((kcl << 5) + (lg << 3)) ^ xr)]);
      }
#pragma unroll
      for (int q = 0; q < 4; ++q) {
        const int cf = (it8 << 2) + q;
        stage((cf + 3) % 64);
        WAIT_VM3();
        __builtin_amdgcn_sched_barrier(0);
        const bf16x8 wf = ring_read(cf);
        acc[q][0] = MFMA16(wf, ib[0], acc[q][0]);
        acc[q][1] = MFMA16(wf, ib[1], acc[q][1]);
      }
    }
    RAW_BARRIER();  // all s_h1 reads done
#pragma unroll
    for (int rt = 0; rt < 2; ++rt) {
      const int r = (rt << 4) + lr;
      bf16x4 hv;
      f32x4 cfv;
#pragma unroll
      for (int i = 0; i < 4; ++i) {
        const float cc = fsig(acc[1][rt][i]) * c1s[rt][i] +
                         fsig(acc[0][rt][i]) * ftanh(acc[2][rt][i]);
        c1s[rt][i] = cc;
        hv[i] = (__bf16)(fsig(acc[3][rt][i]) * ftanh(cc));
        cfv[i] = cc;
      }
      *reinterpret_cast<bf16x4*>(&s_h1[(r << 8) + (e0 ^ xr)]) = hv;
      if (t == 31) {  // c1 final (NT)
        __builtin_nontemporal_store(
            cfv, reinterpret_cast<f32x4*>(out + 73400320 + ((r0 + r) << 8) + e0));
      }
    }
    RAW_BARRIER();  // h1(t) complete in LDS

    // y write: wave writes rows 2wid, 2wid+1, one full 1KB row per instr (NT)
#pragma unroll
    for (int j = 0; j < 2; ++j) {
      const int row = (wid << 1) + j;
      const int xw = (row & 7) << 3;
      const bf16x4 a =
          *reinterpret_cast<const bf16x4*>(&s_h1[(row << 8) + ((l << 2) ^ xw)]);
      f32x4 v;
#pragma unroll
      for (int i = 0; i < 4; ++i) v[i] = (float)a[i];
      __builtin_nontemporal_store(
          v, reinterpret_cast<f32x4*>(out + ((((r0 + row) << 5) + t) << 8) + (l << 2)));
      if (t == 31) {  // h1 final = y[:,31,:] (NT)
        __builtin_nontemporal_store(
            v, reinterpret_cast<f32x4*>(out + 71303168 + ((r0 + row) << 8) + (l << 2)));
      }
    }
    // next-iter ingest targets s_h0 (not read until after next RAW_BARRIER
    // chain); s_h1 rows just read are not rewritten until next epilogue.
  }
}

extern "C" void kernel_launch(void* const* d_in, const int* in_sizes, int n_in,
                              void* d_out, int out_size, void* d_ws, size_t ws_size,
                              hipStream_t stream) {
  const float* traj = (const float*)d_in[0];
  const float* Wemb = (const float*)d_in[1];
  const float* bemb = (const float*)d_in[2];
  const float* W0 = (const float*)d_in[3];
  const float* U0 = (const float*)d_in[4];
  const float* b0 = (const float*)d_in[5];
  const float* W1 = (const float*)d_in[6];
  const float* U1 = (const float*)d_in[7];
  const float* b1 = (const float*)d_in[8];
  float* out = (float*)d_out;

  __bf16* wb0 = (__bf16*)d_ws;  // 768 KB
  __bf16* wb1 = wb0 + 393216;   // 1 MB
  const size_t slab_off = 1835008;
  __bf16* slab = (__bf16*)((char*)d_ws + slab_off);  // 134 MB

  hipLaunchKernelGGL(prep_w0, dim3(1536), dim3(256), 0, stream, W0, U0, wb0);
  hipLaunchKernelGGL(prep_w1, dim3(2048), dim3(256), 0, stream, W1, U1, wb1);
  hipLaunchKernelGGL(lstm_l0, dim3(256), dim3(1024), 0, stream,
                     traj, Wemb, bemb, b0, wb0, out, slab);
  hipLaunchKernelGGL(lstm_l1, dim3(256), dim3(1024), 0, stream,
                     b1, wb1, slab, out);
}